// Round 3
// baseline (782.790 us; speedup 1.0000x reference)
//
#include <hip/hip_runtime.h>

// MaskedBatchNorm2d: B=16, C=64, W=256, H=256, fp32.
// Identity: masked-out locations are exactly +/-0 in all channels, so masked
// per-channel sums == full sums and out = x*inv[c] everywhere (exact-
// cancellation "dirty" locations handled by a ~never-taken fixup path).
//
// R1: global atomics removed (823us -> 594us).
// R2 FAILED: __launch_bounds__(256,8) spilled sAcc[16]/qAcc[16] (+500MB scratch).
// R3: 512thr/8ch-per-wave, no spill, 32 waves/CU (594 -> 564). Learned: harness
//     re-poison fill = 1GiB @ ~162us/iter (fixed overhead, drains into pass1);
//     occupancy doubling bought only ~10% -> pass1 not latency-bound.
// R4 (this round): pass1 restructured for contiguity + minimal barriers:
//     block = (batch, 1024-loc strip); wave reads 4KB contiguous per channel;
//     per-location sums via swizzled conflict-free LDS atomics (ds_add_f32 /
//     ds_or_b32); 2 barriers/block (was 8); no combine phase. finalize/pass2
//     byte-identical behavior, untouched.

#define NB 16
#define CB 64
#define WH 65536               // W*H
#define STRIP 1024             // locations per block
#define GRID1 1024             // 16 batches x 64 strips
#define DIRTY_CAP 512
#define EPS 0.001f

typedef float f32x4 __attribute__((ext_vector_type(4)));

// ws layout (float units):
//  [0 .. 131071]        sqPart[GRID1][128]  (S row 0..63, Q row 64..127) - 512 KB
//  [131072 .. 147455]   nPart[GRID1][16]    (uint)                       -  64 KB
//  [147456]             dirtyCnt (uint, zeroed by memset)
//  [147520 .. 147583]   inv[64]
//  [147584 .. 147599]   padArr[16] (int)
//  [147600 .. 148111]   dirtyLoc[DIRTY_CAP] (int)

__global__ __launch_bounds__(512, 8)
void mbn_pass1(const float* __restrict__ x, float* __restrict__ sqPart,
               unsigned* __restrict__ nPart, unsigned* __restrict__ dirtyCnt,
               int* __restrict__ dirtyLoc) {
    // LDS idx swizzle: location l -> (l&3)*256 + (l>>2), so a lane's 4
    // consecutive locations land at stride-1 addresses in 4 separate 1KB
    // quarters -> ds_add/ds_or are bank-conflict-free across the wave.
    __shared__ float    lds_sum[STRIP];   // per-location channel-sum
    __shared__ unsigned lds_or[STRIP];    // OR of sign-masked value bits
    __shared__ unsigned cnt_lds;
    const int tid  = threadIdx.x;        // 0..511
    const int wave = tid >> 6;           // 0..7
    const int lane = tid & 63;
    const int b    = blockIdx.x >> 6;    // batch
    const int whb  = (blockIdx.x & 63) * STRIP;

    for (int i = tid; i < STRIP; i += 512) { lds_sum[i] = 0.f; lds_or[i] = 0u; }
    if (tid == 0) cnt_lds = 0u;
    __syncthreads();

    float sAcc[8], qAcc[8];              // per-channel S/Q (this wave's 8 ch)
#pragma unroll
    for (int j = 0; j < 8; ++j) { sAcc[j] = 0.f; qAcc[j] = 0.f; }

    // wave w owns channels c = w*8 + j; per channel: 4KB contiguous stream
    const float* xb = x + (((size_t)(b * 64 + wave * 8)) << 16) + whb;
#pragma unroll
    for (int j = 0; j < 8; ++j) {
        const float* p = xb + ((size_t)j << 16);
#pragma unroll
        for (int k = 0; k < 4; ++k) {
            const int l = k * 256 + lane * 4;          // location in strip
            float4 v = *(const float4*)(p + l);
            sAcc[j] += (v.x + v.y) + (v.z + v.w);
            qAcc[j] = fmaf(v.x, v.x, qAcc[j]);
            qAcc[j] = fmaf(v.y, v.y, qAcc[j]);
            qAcc[j] = fmaf(v.z, v.z, qAcc[j]);
            qAcc[j] = fmaf(v.w, v.w, qAcc[j]);
            const int si = (l >> 2);                   // swizzled base (stride-1)
            atomicAdd(&lds_sum[si], v.x);
            atomicAdd(&lds_sum[256 + si], v.y);
            atomicAdd(&lds_sum[512 + si], v.z);
            atomicAdd(&lds_sum[768 + si], v.w);
            atomicOr(&lds_or[si],       __float_as_uint(v.x) & 0x7fffffffu);
            atomicOr(&lds_or[256 + si], __float_as_uint(v.y) & 0x7fffffffu);
            atomicOr(&lds_or[512 + si], __float_as_uint(v.z) & 0x7fffffffu);
            atomicOr(&lds_or[768 + si], __float_as_uint(v.w) & 0x7fffffffu);
        }
    }
    __syncthreads();

    // count kept locations + dirty detection (2 LDS slots per thread)
    unsigned cnt = 0;
#pragma unroll
    for (int h = 0; h < 2; ++h) {
        const int idx = tid + h * 512;
        const float    s = lds_sum[idx];
        const unsigned o = lds_or[idx];
        const bool kept = (s != 0.0f);
        cnt += kept ? 1u : 0u;
        if (!kept && o != 0u) {            // exact cancellation: ~never
            const int l = ((idx & 255) << 2) | (idx >> 8);   // unswizzle
            unsigned di = atomicAdd(dirtyCnt, 1u);
            if (di < DIRTY_CAP) dirtyLoc[di] = (b << 16) | (whb + l);
        }
    }
    for (int off = 32; off; off >>= 1) cnt += __shfl_xor(cnt, off);
    if (lane == 0) atomicAdd(&cnt_lds, cnt);

    // wave-reduce register accumulators; plain stores to this block's ws row
#pragma unroll
    for (int j = 0; j < 8; ++j) {
        float sv = sAcc[j], qv = qAcc[j];
        for (int off = 32; off; off >>= 1) {
            sv += __shfl_xor(sv, off);
            qv += __shfl_xor(qv, off);
        }
        if (lane == 0) {
            sqPart[blockIdx.x * 128 + wave * 8 + j]      = sv;   // S at col c
            sqPart[blockIdx.x * 128 + 64 + wave * 8 + j] = qv;   // Q at 64+c
        }
    }
    __syncthreads();
    if (tid < 16) nPart[blockIdx.x * 16 + tid] = (tid == b) ? cnt_lds : 0u;
}

__global__ __launch_bounds__(1024)
void mbn_finalize(const float* __restrict__ x, const float* __restrict__ sqPart,
                  const unsigned* __restrict__ nPart,
                  const unsigned* __restrict__ dirtyCnt, const int* __restrict__ dirtyLoc,
                  float* __restrict__ inv, int* __restrict__ padOut) {
    __shared__ float red[1024];
    __shared__ float sq[128];
    __shared__ unsigned npar[16][16];
    __shared__ unsigned ntot[16];
    const int t = threadIdx.x;            // 1024 threads
    const int col = t & 127, grp = t >> 7;  // 8 row-groups of 128 rows

    // coalesced reduce of sqPart: thread t sums column col over its 128 rows
    float acc = 0.f;
    const float* p = sqPart + (size_t)grp * 128 * 128 + col;
#pragma unroll 8
    for (int r = 0; r < 128; ++r) acc += p[(size_t)r * 128];
    red[t] = acc;

    if (t < 256) {                         // mask counts: 16 groups x 16 batches
        const int b = t & 15, g2 = t >> 4;
        unsigned s = 0;
        const unsigned* np = nPart + g2 * 64 * 16 + b;
#pragma unroll 8
        for (int r = 0; r < 64; ++r) s += np[r * 16];
        npar[g2][b] = s;
    }
    __syncthreads();
    if (t < 128) {
        float v = 0.f;
#pragma unroll
        for (int g2 = 0; g2 < 8; ++g2) v += red[g2 * 128 + t];
        sq[t] = v;
    }
    if (t < 16) {
        unsigned v = 0;
#pragma unroll
        for (int g2 = 0; g2 < 16; ++g2) v += npar[g2][t];
        ntot[t] = v;
    }
    __syncthreads();

    if (t < 64) {
        const int c = t;
        unsigned nmax = 0;
#pragma unroll
        for (int b = 0; b < NB; ++b) { unsigned nb = ntot[b]; nmax = nb > nmax ? nb : nmax; }
        const float total = (float)(16u * nmax);   // B*Nmax, exact in fp32

        float s = sq[c], q = sq[64 + c];
        // dirty corrections (exclude exact-cancellation locations) — ~never runs
        unsigned cnt = *dirtyCnt; if (cnt > DIRTY_CAP) cnt = DIRTY_CAP;
        for (unsigned i = 0; i < cnt; ++i) {
            int loc = dirtyLoc[i];
            int b = loc >> 16, wh = loc & 65535;
            float v = x[(((size_t)(b * 64 + c)) << 16) + wh];
            s -= v; q -= v * v;
        }
        float p1 = 0.f, p2 = 0.f;
#pragma unroll
        for (int b = 0; b < NB; ++b) {
            float padf = (float)(nmax - ntot[b]);
            float v00  = x[((size_t)(b * 64 + c)) << 16];
            p1 = fmaf(padf, v00, p1);
            p2 = fmaf(padf, v00 * v00, p2);
            if (c == 0) padOut[b] = (int)(nmax - ntot[b]);
        }
        float mean = (s + p1) / total;
        float var  = (q + p2) / total - mean * mean;   // algebraic identity w/ ref
        inv[c] = 1.0f / sqrtf(var + EPS);
    }
}

__global__ __launch_bounds__(256)
void mbn_pass2(const float* __restrict__ x, float* __restrict__ out,
               const float* __restrict__ inv, const unsigned* __restrict__ dirtyCnt,
               const int* __restrict__ dirtyLoc, const int* __restrict__ padArr) {
    // 8192 blocks x 2048 float4: each block's chunk lies in ONE channel plane
    const int blk = blockIdx.x;
    const float sc = inv[(blk >> 3) & 63];             // 8 blocks per plane
    const f32x4* x4 = (const f32x4*)x;
    f32x4* out4 = (f32x4*)out;
    const size_t base = (size_t)blk * 2048 + threadIdx.x;
#pragma unroll
    for (int k = 0; k < 8; ++k) {
        size_t i = base + (size_t)k * 256;
        f32x4 v = x4[i];
        v *= sc;
        __builtin_nontemporal_store(v, &out4[i]);      // out never re-read
    }

    // folded fixup: each block patches only its OWN float range (no cross-
    // block ordering needed). dirtyCnt == 0 in practice -> uniform early out.
    unsigned cnt = *dirtyCnt;
    if (cnt != 0) {
        __syncthreads();                               // order NT stores vs patch
        if (threadIdx.x == 0) {
            if (cnt > DIRTY_CAP) cnt = DIRTY_CAP;
            const int bb = blk >> 9, cc = (blk >> 3) & 63, seg = blk & 7;
            const int lo = seg * 8192, hi = lo + 8192;
            for (unsigned i = 0; i < cnt; ++i) {
                int loc = dirtyLoc[i];
                int b = loc >> 16, wh = loc & 65535;
                if (b != bb || wh < lo || wh >= hi) continue;
                if (wh == 0 && padArr[b] > 0) continue;   // (0,0) override wins
                size_t idx = (((size_t)(b * 64 + cc)) << 16) + wh;
                out[idx] = x[idx];                        // m=0 w/ nonzero x: out = x
            }
        }
    }
}

extern "C" void kernel_launch(void* const* d_in, const int* in_sizes, int n_in,
                              void* d_out, int out_size, void* d_ws, size_t ws_size,
                              hipStream_t stream) {
    const float* x = (const float*)d_in[0];
    float* out = (float*)d_out;
    float* wsf = (float*)d_ws;

    float*    sqPart   = wsf;
    unsigned* nPart    = (unsigned*)(wsf + 131072);
    unsigned* dirtyCnt = (unsigned*)(wsf + 147456);
    float*    inv      = wsf + 147520;
    int*      padArr   = (int*)(wsf + 147584);
    int*      dirtyLoc = (int*)(wsf + 147600);

    // only dirtyCnt needs zeroing (partials are written unconditionally)
    hipMemsetAsync((char*)d_ws + 147456 * 4, 0, 64, stream);

    mbn_pass1<<<GRID1, 512, 0, stream>>>(x, sqPart, nPart, dirtyCnt, dirtyLoc);
    mbn_finalize<<<1, 1024, 0, stream>>>(x, sqPart, nPart, dirtyCnt, dirtyLoc, inv, padArr);
    mbn_pass2<<<8192, 256, 0, stream>>>(x, out, inv, dirtyCnt, dirtyLoc, padArr);
}